// Round 5
// baseline (343.820 us; speedup 1.0000x reference)
//
#include <hip/hip_runtime.h>
#include <cstdint>
#include <cstddef>

// x[B=512, L=32, H=32, D=128]; per (l,h): Linear(128->128) -> GELU -> Linear(128->128)
#define LH      1024
#define Dd      128
#define BT      128           // batch rows per block
#define MT      8             // 16-row A fragments per block
#define XSTRIDE (LH * Dd)

typedef __attribute__((ext_vector_type(8))) short bf16x8;
typedef __attribute__((ext_vector_type(4))) float f32x4;

// native cast -> compiler emits v_cvt_pk_bf16_f32 (guide m240)
static __device__ __forceinline__ short f2bf(float f) {
  return __builtin_bit_cast(short, (__bf16)f);
}

// tanh-form GELU as one sigmoid: x*sigmoid(1.5957691(x + 0.044715 x^3)).
// |diff| vs exact-erf gelu ~3e-3 << 0.185 threshold; ~8 VALU vs ~25 for erff.
static __device__ __forceinline__ float gelu_fast(float v) {
  float v2 = v * v;
  float u2 = v * (1.5957691216f + 0.0713548163f * v2);
  return v / (1.0f + __expf(-u2));
}

__global__ __launch_bounds__(256, 4) void fused_mlp_kernel(
    const float* __restrict__ x, const float* __restrict__ W1,
    const float* __restrict__ b1, const float* __restrict__ W2,
    const float* __restrict__ b2, float* __restrict__ out) {
  // bf16 H tile [b][e], row stride 256 B, XOR-swizzled (byte ^= (row&7)<<4).
  __shared__ alignas(16) short Hs[BT * Dd];   // 32 KB

  const int tid  = threadIdx.x;
  const int lane = tid & 63;
  const int wid  = tid >> 6;     // 4 waves, each owns 32 N-columns
  const int lr   = lane & 15;
  const int lg   = lane >> 4;

  const int bid = blockIdx.x;
  // Same-lh blocks ADJACENT in dispatch: the 4 W-sharers are co-resident,
  // W fetched from HBM once and shared via die-level L3 (R4 post-mortem:
  // 1024-apart spacing required W to survive a whole generation in L3 and
  // failed once streaming exceeded 256 MB/generation).
  const int lh = bid >> 2;
  const int bt = bid & 3;

  const float* w1 = W1 + (size_t)lh * (Dd * Dd);
  const float* w2 = W2 + (size_t)lh * (Dd * Dd);
  const int n0 = wid * 32;

  // bias values for this lane's two output columns (folded into MFMA C-init)
  const float bb1_0 = b1[lh * Dd + n0 + lr];
  const float bb1_1 = b1[lh * Dd + n0 + 16 + lr];
  const float bb2_0 = b2[lh * Dd + n0 + lr];
  const float bb2_1 = b2[lh * Dd + n0 + 16 + lr];

  const float* xa = x + ((size_t)(bt * BT + lr) * LH + lh) * Dd + lg * 8;

  // ---------------- GEMM1: H = gelu(X @ W1 + b1), W2 prefetched alongside ----
  f32x4 acc[MT][2];
#pragma unroll
  for (int mt = 0; mt < MT; ++mt) {
    acc[mt][0] = (f32x4){bb1_0, bb1_0, bb1_0, bb1_0};
    acc[mt][1] = (f32x4){bb1_1, bb1_1, bb1_1, bb1_1};
  }

  bf16x8 bw2[4][2];   // all of this wave's W2 fragments, loaded during GEMM1

#pragma unroll
  for (int ks = 0; ks < 4; ++ks) {
    const int k0 = ks * 32 + lg * 8;
    bf16x8 af[MT];
#pragma unroll
    for (int mt = 0; mt < MT; ++mt) {
      const float4* p = (const float4*)(xa + (size_t)mt * 16 * XSTRIDE + ks * 32);
      float4 u = p[0], v = p[1];
      bf16x8 a;
      a[0] = f2bf(u.x); a[1] = f2bf(u.y); a[2] = f2bf(u.z); a[3] = f2bf(u.w);
      a[4] = f2bf(v.x); a[5] = f2bf(v.y); a[6] = f2bf(v.z); a[7] = f2bf(v.w);
      af[mt] = a;
    }
    bf16x8 bw[2];
#pragma unroll
    for (int nt = 0; nt < 2; ++nt) {
      const float* wp = w1 + (size_t)k0 * Dd + n0 + nt * 16 + lr;
      bf16x8 b;
#pragma unroll
      for (int j = 0; j < 8; ++j) b[j] = f2bf(wp[j * Dd]);
      bw[nt] = b;
    }
    // W2 prefetch: hide its HBM/L3 latency under GEMM1 so GEMM2 starts
    // immediately after the barrier.
#pragma unroll
    for (int nt = 0; nt < 2; ++nt) {
      const float* wp = w2 + (size_t)k0 * Dd + n0 + nt * 16 + lr;
      bf16x8 b;
#pragma unroll
      for (int j = 0; j < 8; ++j) b[j] = f2bf(wp[j * Dd]);
      bw2[ks][nt] = b;
    }
#pragma unroll
    for (int mt = 0; mt < MT; ++mt)
#pragma unroll
      for (int nt = 0; nt < 2; ++nt)
        acc[mt][nt] = __builtin_amdgcn_mfma_f32_16x16x32_bf16(af[mt], bw[nt], acc[mt][nt], 0, 0, 0);
  }

  // epilogue 1: GELU -> bf16 -> swizzled LDS
#pragma unroll
  for (int mt = 0; mt < MT; ++mt)
#pragma unroll
    for (int nt = 0; nt < 2; ++nt) {
      const int e = n0 + nt * 16 + lr;
#pragma unroll
      for (int r = 0; r < 4; ++r) {
        const int b = mt * 16 + lg * 4 + r;      // C/D row = (lane>>4)*4 + reg
        float v = gelu_fast(acc[mt][nt][r]);
        const int off = (b * 256 + e * 2) ^ ((b & 7) << 4);
        *(short*)((char*)Hs + off) = f2bf(v);
      }
    }
  __syncthreads();

  // ---------------- GEMM2: out = H @ W2 + b2 (W2 already in regs) ----------
  f32x4 acc2[MT][2];
#pragma unroll
  for (int mt = 0; mt < MT; ++mt) {
    acc2[mt][0] = (f32x4){bb2_0, bb2_0, bb2_0, bb2_0};
    acc2[mt][1] = (f32x4){bb2_1, bb2_1, bb2_1, bb2_1};
  }

#pragma unroll
  for (int ks = 0; ks < 4; ++ks) {
    const int k0 = ks * 32 + lg * 8;
#pragma unroll
    for (int mt = 0; mt < MT; ++mt) {
      const int b = mt * 16 + lr;
      const int off = (b * 256 + k0 * 2) ^ ((b & 7) << 4);   // 16B-aligned
      bf16x8 a = *(const bf16x8*)((const char*)Hs + off);
#pragma unroll
      for (int nt = 0; nt < 2; ++nt)
        acc2[mt][nt] = __builtin_amdgcn_mfma_f32_16x16x32_bf16(a, bw2[ks][nt], acc2[mt][nt], 0, 0, 0);
    }
  }

  // epilogue 2: regular f32 stores
  {
    float* ob = out + ((size_t)(bt * BT) * LH + lh) * Dd;
#pragma unroll
    for (int mt = 0; mt < MT; ++mt)
#pragma unroll
      for (int nt = 0; nt < 2; ++nt) {
        const int e = n0 + nt * 16 + lr;
#pragma unroll
        for (int r = 0; r < 4; ++r) {
          const int b = mt * 16 + lg * 4 + r;
          ob[(size_t)b * XSTRIDE + e] = acc2[mt][nt][r];
        }
      }
  }
}

extern "C" void kernel_launch(void* const* d_in, const int* in_sizes, int n_in,
                              void* d_out, int out_size, void* d_ws, size_t ws_size,
                              hipStream_t stream) {
  (void)in_sizes; (void)n_in; (void)d_ws; (void)ws_size; (void)out_size;
  const float* x  = (const float*)d_in[0];
  const float* W1 = (const float*)d_in[1];
  const float* b1 = (const float*)d_in[2];
  const float* W2 = (const float*)d_in[3];
  const float* b2 = (const float*)d_in[4];
  float* out = (float*)d_out;
  fused_mlp_kernel<<<dim3(4096), dim3(256), 0, stream>>>(x, W1, b1, W2, b2, out);
}

// Round 6
// 221.058 us; speedup vs baseline: 1.5553x; 1.5553x over previous
//
#include <hip/hip_runtime.h>
#include <cstdint>
#include <cstddef>

// x[B=512, L=32, H=32, D=128]; per (l,h): Linear(128->128) -> GELU -> Linear(128->128)
#define LH      1024
#define Dd      128
#define BT      64            // batch rows per block -> x tile 32 KB f32 in LDS
#define XSTRIDE (LH * Dd)

typedef __attribute__((ext_vector_type(8))) short bf16x8;
typedef __attribute__((ext_vector_type(4))) float f32x4;
typedef const __attribute__((address_space(1))) uint32_t gu32;
typedef __attribute__((address_space(3))) uint32_t lu32;

// native cast -> v_cvt_pk_bf16_f32 (guide m240)
static __device__ __forceinline__ short f2bf(float f) {
  return __builtin_bit_cast(short, (__bf16)f);
}

// tanh-form GELU as one sigmoid; |diff| vs erf-gelu ~3e-3 << 0.185 threshold
static __device__ __forceinline__ float gelu_fast(float v) {
  float v2 = v * v;
  float u2 = v * (1.5957691216f + 0.0713548163f * v2);
  return v / (1.0f + __expf(-u2));
}

__global__ __launch_bounds__(256, 4) void fused_mlp_kernel(
    const float* __restrict__ x, const float* __restrict__ W1,
    const float* __restrict__ b1, const float* __restrict__ W2,
    const float* __restrict__ b2, float* __restrict__ out) {
  // LDS 32 KB: x f32 [64 rows][32 chunks of 16B], chunk-index XOR-swizzled
  // (slot c' holds global chunk c = c' ^ (row&15)) -- swizzle applied on the
  // GLOBAL source address because global_load_lds writes LDS linearly
  // (guide m104/m173). H bf16 [64][128] overlays bytes 0..16K after barrier.
  __shared__ alignas(16) char smem[BT * Dd * 4];

  const int tid  = threadIdx.x;
  const int lane = tid & 63;
  const int wid  = tid >> 6;     // 4 waves, each owns 32 N-columns
  const int lr   = lane & 15;
  const int lg   = lane >> 4;

  const int bid = blockIdx.x;
  const int lh  = bid >> 3;      // 8 consecutive blocks share this lh's W
  const int bt  = bid & 7;

  const float* w1 = W1 + (size_t)lh * (Dd * Dd);
  const float* w2 = W2 + (size_t)lh * (Dd * Dd);
  const int n0 = wid * 32;

  // ---- stage x tile to LDS via VGPR-free DMA: 8 issues/wave, 32 KB in flight
  {
    const float* xblk = x + ((size_t)(bt * BT) * LH + lh) * Dd;
#pragma unroll
    for (int i = 0; i < 8; ++i) {
      const int slot = wid * 8 + i;          // wave-uniform LDS 1KB slot
      const int row  = slot * 2 + (lane >> 5);
      const int cp   = lane & 31;            // chunk position in LDS
      const int c    = cp ^ (row & 15);      // global chunk index (bijective)
      const float* g = xblk + (size_t)row * XSTRIDE + c * 4;
      __builtin_amdgcn_global_load_lds((gu32*)g, (lu32*)(smem + slot * 1024),
                                       16, 0, 0);
    }
  }

  // biases folded into MFMA C-init
  const float bb1_0 = b1[lh * Dd + n0 + lr];
  const float bb1_1 = b1[lh * Dd + n0 + 16 + lr];
  const float bb2_0 = b2[lh * Dd + n0 + lr];
  const float bb2_1 = b2[lh * Dd + n0 + 16 + lr];

  // W1 ks=0 fragments loaded pre-barrier (drained by the same barrier as DMA)
  bf16x8 bw1[2];
  {
    const int k0 = lg * 8;
#pragma unroll
    for (int nt = 0; nt < 2; ++nt) {
      const float* wp = w1 + (size_t)k0 * Dd + n0 + nt * 16 + lr;
      bf16x8 b;
#pragma unroll
      for (int j = 0; j < 8; ++j) b[j] = f2bf(wp[j * Dd]);
      bw1[nt] = b;
    }
  }

  f32x4 acc[4][2];
#pragma unroll
  for (int mt = 0; mt < 4; ++mt) {
    acc[mt][0] = (f32x4){bb1_0, bb1_0, bb1_0, bb1_0};
    acc[mt][1] = (f32x4){bb1_1, bb1_1, bb1_1, bb1_1};
  }
  bf16x8 bw2[4][2];

  __syncthreads();   // drains DMA (vmcnt 0) + makes x tile visible

  // ---------------- GEMM1: H = gelu(X @ W1 + b1) ----------------
#pragma unroll
  for (int ks = 0; ks < 4; ++ks) {
    // software-pipeline W1[ks+1]; W2[ks] to regs for the post-barrier GEMM2
    bf16x8 bw1n[2];
    if (ks < 3) {
      const int k0 = (ks + 1) * 32 + lg * 8;
#pragma unroll
      for (int nt = 0; nt < 2; ++nt) {
        const float* wp = w1 + (size_t)k0 * Dd + n0 + nt * 16 + lr;
        bf16x8 b;
#pragma unroll
        for (int j = 0; j < 8; ++j) b[j] = f2bf(wp[j * Dd]);
        bw1n[nt] = b;
      }
    }
    {
      const int k0 = ks * 32 + lg * 8;
#pragma unroll
      for (int nt = 0; nt < 2; ++nt) {
        const float* wp = w2 + (size_t)k0 * Dd + n0 + nt * 16 + lr;
        bf16x8 b;
#pragma unroll
        for (int j = 0; j < 8; ++j) b[j] = f2bf(wp[j * Dd]);
        bw2[ks][nt] = b;
      }
    }
    // A fragments from swizzled f32 LDS (two b128 per frag, bank-uniform)
    bf16x8 af[4];
#pragma unroll
    for (int mt = 0; mt < 4; ++mt) {
      const int row = mt * 16 + lr;
      const int c0  = ks * 8 + lg * 2;
      const int m   = row & 15;
      const float4 lo = *(const float4*)(smem + row * 512 + ((c0)     ^ m) * 16);
      const float4 hi = *(const float4*)(smem + row * 512 + ((c0 + 1) ^ m) * 16);
      bf16x8 a;
      a[0] = f2bf(lo.x); a[1] = f2bf(lo.y); a[2] = f2bf(lo.z); a[3] = f2bf(lo.w);
      a[4] = f2bf(hi.x); a[5] = f2bf(hi.y); a[6] = f2bf(hi.z); a[7] = f2bf(hi.w);
      af[mt] = a;
    }
#pragma unroll
    for (int mt = 0; mt < 4; ++mt)
#pragma unroll
      for (int nt = 0; nt < 2; ++nt)
        acc[mt][nt] = __builtin_amdgcn_mfma_f32_16x16x32_bf16(af[mt], bw1[nt], acc[mt][nt], 0, 0, 0);
    bw1[0] = bw1n[0];
    bw1[1] = bw1n[1];
  }

  // GELU in regs (VALU work before the barrier), then overlay-write H
  short hv[4][2][4];
#pragma unroll
  for (int mt = 0; mt < 4; ++mt)
#pragma unroll
    for (int nt = 0; nt < 2; ++nt)
#pragma unroll
      for (int r = 0; r < 4; ++r)
        hv[mt][nt][r] = f2bf(gelu_fast(acc[mt][nt][r]));

  __syncthreads();   // all waves done reading x LDS -> safe to overlay H

#pragma unroll
  for (int mt = 0; mt < 4; ++mt)
#pragma unroll
    for (int nt = 0; nt < 2; ++nt) {
      const int e = n0 + nt * 16 + lr;
#pragma unroll
      for (int r = 0; r < 4; ++r) {
        const int b = mt * 16 + lg * 4 + r;    // C/D row = (lane>>4)*4 + reg
        const int off = (b * 256 + e * 2) ^ ((b & 7) << 4);
        *(short*)(smem + off) = hv[mt][nt][r];
      }
    }
  __syncthreads();   // H visible

  // ---------------- GEMM2: out = H @ W2 + b2 (W2 already in regs) ----------
  f32x4 acc2[4][2];
#pragma unroll
  for (int mt = 0; mt < 4; ++mt) {
    acc2[mt][0] = (f32x4){bb2_0, bb2_0, bb2_0, bb2_0};
    acc2[mt][1] = (f32x4){bb2_1, bb2_1, bb2_1, bb2_1};
  }

#pragma unroll
  for (int ks = 0; ks < 4; ++ks) {
    const int k2 = (ks * 32 + lg * 8) * 2;     // byte offset of 16B H granule
#pragma unroll
    for (int mt = 0; mt < 4; ++mt) {
      const int b = mt * 16 + lr;
      const int off = (b * 256 + k2) ^ ((b & 7) << 4);
      bf16x8 a = *(const bf16x8*)(smem + off);
#pragma unroll
      for (int nt = 0; nt < 2; ++nt)
        acc2[mt][nt] = __builtin_amdgcn_mfma_f32_16x16x32_bf16(a, bw2[ks][nt], acc2[mt][nt], 0, 0, 0);
    }
  }

  // epilogue: regular f32 stores (64B segments per 16-lane group)
  {
    float* ob = out + ((size_t)(bt * BT) * LH + lh) * Dd;
#pragma unroll
    for (int mt = 0; mt < 4; ++mt)
#pragma unroll
      for (int nt = 0; nt < 2; ++nt) {
        const int e = n0 + nt * 16 + lr;
#pragma unroll
        for (int r = 0; r < 4; ++r) {
          const int b = mt * 16 + lg * 4 + r;
          ob[(size_t)b * XSTRIDE + e] = acc2[mt][nt][r];
        }
      }
  }
}

extern "C" void kernel_launch(void* const* d_in, const int* in_sizes, int n_in,
                              void* d_out, int out_size, void* d_ws, size_t ws_size,
                              hipStream_t stream) {
  (void)in_sizes; (void)n_in; (void)d_ws; (void)ws_size; (void)out_size;
  const float* x  = (const float*)d_in[0];
  const float* W1 = (const float*)d_in[1];
  const float* b1 = (const float*)d_in[2];
  const float* W2 = (const float*)d_in[3];
  const float* b2 = (const float*)d_in[4];
  float* out = (float*)d_out;
  fused_mlp_kernel<<<dim3(8192), dim3(256), 0, stream>>>(x, W1, b1, W2, b2, out);
}

// Round 7
// 193.413 us; speedup vs baseline: 1.7776x; 1.1429x over previous
//
#include <hip/hip_runtime.h>
#include <cstdint>
#include <cstddef>

// x[B=512, L=32, H=32, D=128]; per (l,h): Linear(128->128) -> GELU -> Linear(128->128)
#define LH      1024
#define Dd      128
#define BT      64            // batch rows per block -> x tile 32 KB f32 in LDS
#define XSTRIDE (LH * Dd)

typedef __attribute__((ext_vector_type(8))) short bf16x8;
typedef __attribute__((ext_vector_type(4))) float f32x4;
typedef const __attribute__((address_space(1))) uint32_t gu32;
typedef __attribute__((address_space(3))) uint32_t lu32;

// native cast -> v_cvt_pk_bf16_f32 (guide m240)
static __device__ __forceinline__ short f2bf(float f) {
  return __builtin_bit_cast(short, (__bf16)f);
}

// tanh-form GELU as one sigmoid; |diff| vs erf-gelu ~3e-3 << 0.185 threshold
static __device__ __forceinline__ float gelu_fast(float v) {
  float v2 = v * v;
  float u2 = v * (1.5957691216f + 0.0713548163f * v2);
  return v / (1.0f + __expf(-u2));
}

__global__ __launch_bounds__(256, 4) void fused_mlp_kernel(
    const float* __restrict__ x, const float* __restrict__ W1,
    const float* __restrict__ b1, const float* __restrict__ W2,
    const float* __restrict__ b2, float* __restrict__ out) {
  // LDS 32 KB: x f32 [64 rows][32 chunks of 16B], chunk-index XOR-swizzled
  // (slot c' holds global chunk c = c' ^ (row&15)) -- swizzle applied on the
  // GLOBAL source address because global_load_lds writes LDS linearly
  // (guide m104/m173). H bf16 [64][128] overlays bytes 0..16K after barrier.
  __shared__ alignas(16) char smem[BT * Dd * 4];

  const int tid  = threadIdx.x;
  const int lane = tid & 63;
  const int wid  = tid >> 6;     // 4 waves, each owns 32 N-columns
  const int lr   = lane & 15;
  const int lg   = lane >> 4;

  const int bid = blockIdx.x;
  // XCD-colocation (R7): XCD = bid%8 (guide m09). One lh's 8 bt-blocks get 8
  // CONSECUTIVE slots on the SAME XCD -> W (128 KB) lives in that XCD's 4MB
  // L2 and is hit 8x, instead of being fetched by all 8 XCDs (R6: FETCH 661MB).
  const int lh = (bid & 7) * 128 + (bid >> 6);
  const int bt = (bid >> 3) & 7;

  const float* w1 = W1 + (size_t)lh * (Dd * Dd);
  const float* w2 = W2 + (size_t)lh * (Dd * Dd);
  const int n0 = wid * 32;

  // ---- stage x tile to LDS via VGPR-free DMA: 8 issues/wave, 32 KB in flight
  {
    const float* xblk = x + ((size_t)(bt * BT) * LH + lh) * Dd;
#pragma unroll
    for (int i = 0; i < 8; ++i) {
      const int slot = wid * 8 + i;          // wave-uniform LDS 1KB slot
      const int row  = slot * 2 + (lane >> 5);
      const int cp   = lane & 31;            // chunk position in LDS
      const int c    = cp ^ (row & 15);      // global chunk index (bijective)
      const float* g = xblk + (size_t)row * XSTRIDE + c * 4;
      __builtin_amdgcn_global_load_lds((gu32*)g, (lu32*)(smem + slot * 1024),
                                       16, 0, 0);
    }
  }

  // biases folded into MFMA C-init
  const float bb1_0 = b1[lh * Dd + n0 + lr];
  const float bb1_1 = b1[lh * Dd + n0 + 16 + lr];
  const float bb2_0 = b2[lh * Dd + n0 + lr];
  const float bb2_1 = b2[lh * Dd + n0 + 16 + lr];

  // W1 ks=0 fragments loaded pre-barrier (drained by the same barrier as DMA)
  bf16x8 bw1[2];
  {
    const int k0 = lg * 8;
#pragma unroll
    for (int nt = 0; nt < 2; ++nt) {
      const float* wp = w1 + (size_t)k0 * Dd + n0 + nt * 16 + lr;
      bf16x8 b;
#pragma unroll
      for (int j = 0; j < 8; ++j) b[j] = f2bf(wp[j * Dd]);
      bw1[nt] = b;
    }
  }

  f32x4 acc[4][2];
#pragma unroll
  for (int mt = 0; mt < 4; ++mt) {
    acc[mt][0] = (f32x4){bb1_0, bb1_0, bb1_0, bb1_0};
    acc[mt][1] = (f32x4){bb1_1, bb1_1, bb1_1, bb1_1};
  }
  bf16x8 bw2[4][2];

  __syncthreads();   // drains DMA (vmcnt 0) + makes x tile visible

  // ---------------- GEMM1: H = gelu(X @ W1 + b1) ----------------
#pragma unroll
  for (int ks = 0; ks < 4; ++ks) {
    // software-pipeline W1[ks+1]; W2[ks] to regs for the post-barrier GEMM2
    bf16x8 bw1n[2];
    if (ks < 3) {
      const int k0 = (ks + 1) * 32 + lg * 8;
#pragma unroll
      for (int nt = 0; nt < 2; ++nt) {
        const float* wp = w1 + (size_t)k0 * Dd + n0 + nt * 16 + lr;
        bf16x8 b;
#pragma unroll
        for (int j = 0; j < 8; ++j) b[j] = f2bf(wp[j * Dd]);
        bw1n[nt] = b;
      }
    }
    {
      const int k0 = ks * 32 + lg * 8;
#pragma unroll
      for (int nt = 0; nt < 2; ++nt) {
        const float* wp = w2 + (size_t)k0 * Dd + n0 + nt * 16 + lr;
        bf16x8 b;
#pragma unroll
        for (int j = 0; j < 8; ++j) b[j] = f2bf(wp[j * Dd]);
        bw2[ks][nt] = b;
      }
    }
    // A fragments from swizzled f32 LDS (two b128 per frag, bank-uniform)
    bf16x8 af[4];
#pragma unroll
    for (int mt = 0; mt < 4; ++mt) {
      const int row = mt * 16 + lr;
      const int c0  = ks * 8 + lg * 2;
      const int m   = row & 15;
      const float4 lo = *(const float4*)(smem + row * 512 + ((c0)     ^ m) * 16);
      const float4 hi = *(const float4*)(smem + row * 512 + ((c0 + 1) ^ m) * 16);
      bf16x8 a;
      a[0] = f2bf(lo.x); a[1] = f2bf(lo.y); a[2] = f2bf(lo.z); a[3] = f2bf(lo.w);
      a[4] = f2bf(hi.x); a[5] = f2bf(hi.y); a[6] = f2bf(hi.z); a[7] = f2bf(hi.w);
      af[mt] = a;
    }
#pragma unroll
    for (int mt = 0; mt < 4; ++mt)
#pragma unroll
      for (int nt = 0; nt < 2; ++nt)
        acc[mt][nt] = __builtin_amdgcn_mfma_f32_16x16x32_bf16(af[mt], bw1[nt], acc[mt][nt], 0, 0, 0);
    bw1[0] = bw1n[0];
    bw1[1] = bw1n[1];
  }

  // GELU in regs (VALU work before the barrier), then overlay-write H
  short hv[4][2][4];
#pragma unroll
  for (int mt = 0; mt < 4; ++mt)
#pragma unroll
    for (int nt = 0; nt < 2; ++nt)
#pragma unroll
      for (int r = 0; r < 4; ++r)
        hv[mt][nt][r] = f2bf(gelu_fast(acc[mt][nt][r]));

  __syncthreads();   // all waves done reading x LDS -> safe to overlay H

#pragma unroll
  for (int mt = 0; mt < 4; ++mt)
#pragma unroll
    for (int nt = 0; nt < 2; ++nt) {
      const int e = n0 + nt * 16 + lr;
#pragma unroll
      for (int r = 0; r < 4; ++r) {
        const int b = mt * 16 + lg * 4 + r;    // C/D row = (lane>>4)*4 + reg
        const int off = (b * 256 + e * 2) ^ ((b & 7) << 4);
        *(short*)(smem + off) = hv[mt][nt][r];
      }
    }
  __syncthreads();   // H visible

  // ---------------- GEMM2: out = H @ W2 + b2 (W2 already in regs) ----------
  f32x4 acc2[4][2];
#pragma unroll
  for (int mt = 0; mt < 4; ++mt) {
    acc2[mt][0] = (f32x4){bb2_0, bb2_0, bb2_0, bb2_0};
    acc2[mt][1] = (f32x4){bb2_1, bb2_1, bb2_1, bb2_1};
  }

#pragma unroll
  for (int ks = 0; ks < 4; ++ks) {
    const int k2 = (ks * 32 + lg * 8) * 2;     // byte offset of 16B H granule
#pragma unroll
    for (int mt = 0; mt < 4; ++mt) {
      const int b = mt * 16 + lr;
      const int off = (b * 256 + k2) ^ ((b & 7) << 4);
      bf16x8 a = *(const bf16x8*)(smem + off);
#pragma unroll
      for (int nt = 0; nt < 2; ++nt)
        acc2[mt][nt] = __builtin_amdgcn_mfma_f32_16x16x32_bf16(a, bw2[ks][nt], acc2[mt][nt], 0, 0, 0);
    }
  }

  // epilogue: regular f32 stores (64B segments per 16-lane group)
  {
    float* ob = out + ((size_t)(bt * BT) * LH + lh) * Dd;
#pragma unroll
    for (int mt = 0; mt < 4; ++mt)
#pragma unroll
      for (int nt = 0; nt < 2; ++nt) {
        const int e = n0 + nt * 16 + lr;
#pragma unroll
        for (int r = 0; r < 4; ++r) {
          const int b = mt * 16 + lg * 4 + r;
          ob[(size_t)b * XSTRIDE + e] = acc2[mt][nt][r];
        }
      }
  }
}

extern "C" void kernel_launch(void* const* d_in, const int* in_sizes, int n_in,
                              void* d_out, int out_size, void* d_ws, size_t ws_size,
                              hipStream_t stream) {
  (void)in_sizes; (void)n_in; (void)d_ws; (void)ws_size; (void)out_size;
  const float* x  = (const float*)d_in[0];
  const float* W1 = (const float*)d_in[1];
  const float* b1 = (const float*)d_in[2];
  const float* W2 = (const float*)d_in[3];
  const float* b2 = (const float*)d_in[4];
  float* out = (float*)d_out;
  fused_mlp_kernel<<<dim3(8192), dim3(256), 0, stream>>>(x, W1, b1, W2, b2, out);
}

// Round 8
// 185.785 us; speedup vs baseline: 1.8506x; 1.0411x over previous
//
#include <hip/hip_runtime.h>
#include <cstdint>
#include <cstddef>

// x[B=512, L=32, H=32, D=128]; per (l,h): Linear(128->128) -> GELU -> Linear(128->128)
#define LH      1024
#define Dd      128
#define BT      64            // batch rows per block -> x tile 32 KB f32 in LDS
#define XSTRIDE (LH * Dd)
#define WB_PER_LH 65536       // per-lh repacked W: 2 layers * 32 KB bf16 fragments

typedef __attribute__((ext_vector_type(8))) short bf16x8;
typedef __attribute__((ext_vector_type(4))) float f32x4;
typedef const __attribute__((address_space(1))) uint32_t gu32;
typedef __attribute__((address_space(3))) uint32_t lu32;

static __device__ __forceinline__ short f2bf(float f) {
  return __builtin_bit_cast(short, (__bf16)f);
}

// tanh-form GELU as one sigmoid; |diff| vs erf-gelu ~3e-3 << 0.185 threshold
static __device__ __forceinline__ float gelu_fast(float v) {
  float v2 = v * v;
  float u2 = v * (1.5957691216f + 0.0713548163f * v2);
  return v / (1.0f + __expf(-u2));
}

// ---------------- pre-pass: W -> bf16 fragment layout in d_ws ---------------
// entry e in [0,2048) per (lh,layer): ks=e>>9, n16=(e>>6)&7, ln=e&63.
// fragment = 8 bf16 {W[ks*32+lg*8+j][n16*16+lr]} stored contiguous (16 B).
__global__ __launch_bounds__(256, 2) void repack_w(
    const float* __restrict__ W1, const float* __restrict__ W2,
    char* __restrict__ wb) {
  const int lh = blockIdx.x;
  const int t  = threadIdx.x;
#pragma unroll
  for (int layer = 0; layer < 2; ++layer) {
    const float* w = (layer ? W2 : W1) + (size_t)lh * (Dd * Dd);
    char* dst = wb + (size_t)lh * WB_PER_LH + layer * 32768;
#pragma unroll
    for (int i = 0; i < 8; ++i) {
      const int e  = i * 256 + t;
      const int ks = e >> 9, n16 = (e >> 6) & 7, ln = e & 63;
      const int lr = ln & 15, lg = ln >> 4;
      const float* wp = w + (size_t)(ks * 32 + lg * 8) * Dd + n16 * 16 + lr;
      bf16x8 b;
#pragma unroll
      for (int j = 0; j < 8; ++j) b[j] = f2bf(wp[j * Dd]);
      *(bf16x8*)(dst + (size_t)e * 16) = b;
    }
  }
}

// ---------------- main kernel (repacked-W path) ----------------
__global__ __launch_bounds__(256, 4) void fused_mlp_wb(
    const float* __restrict__ x, const char* __restrict__ wb,
    const float* __restrict__ b1, const float* __restrict__ b2,
    float* __restrict__ out) {
  // LDS 32 KB: x f32 [64 rows][32 chunks of 16B], chunk-XOR-swizzled on the
  // GLOBAL src addr (global_load_lds writes linearly, m104/m173).
  // H bf16 [64][128] overlays bytes 0..16K after barrier.
  __shared__ alignas(16) char smem[BT * Dd * 4];

  const int tid  = threadIdx.x;
  const int lane = tid & 63;
  const int wid  = tid >> 6;     // 4 waves, each owns 32 N-columns
  const int lr   = lane & 15;
  const int lg   = lane >> 4;

  const int bid = blockIdx.x;
  // XCD-colocation (R7): one lh's 8 bt-blocks take 8 consecutive same-XCD
  // slots -> W served from that XCD's L2/L3 (FETCH 661->197 MB).
  const int lh = (bid & 7) * 128 + (bid >> 6);
  const int bt = (bid >> 3) & 7;

  const int n0 = wid * 32;

  // ---- stage x tile to LDS via VGPR-free DMA: 8 issues/wave, 32 KB in flight
  {
    const float* xblk = x + ((size_t)(bt * BT) * LH + lh) * Dd;
#pragma unroll
    for (int i = 0; i < 8; ++i) {
      const int slot = wid * 8 + i;          // wave-uniform LDS 1KB slot
      const int row  = slot * 2 + (lane >> 5);
      const int cp   = lane & 31;            // chunk position in LDS
      const int c    = cp ^ (row & 15);      // global chunk index (bijective)
      const float* g = xblk + (size_t)row * XSTRIDE + c * 4;
      __builtin_amdgcn_global_load_lds((gu32*)g, (lu32*)(smem + slot * 1024),
                                       16, 0, 0);
    }
  }

  // ---- preload ALL W fragments (16 x b128, contiguous 1KB/wave) BEFORE the
  // barrier: in flight alongside the DMA drain; GEMM loops touch no global W.
  const char* wblh = wb + (size_t)lh * WB_PER_LH;
  bf16x8 bw1[4][2], bw2[4][2];
#pragma unroll
  for (int ks = 0; ks < 4; ++ks)
#pragma unroll
    for (int nt = 0; nt < 2; ++nt) {
      const size_t fo = (size_t)((ks * 8 + wid * 2 + nt) * 64 + lane) * 16;
      bw1[ks][nt] = *(const bf16x8*)(wblh + fo);
      bw2[ks][nt] = *(const bf16x8*)(wblh + 32768 + fo);
    }

  // biases folded into MFMA C-init
  const float bb1_0 = b1[lh * Dd + n0 + lr];
  const float bb1_1 = b1[lh * Dd + n0 + 16 + lr];
  const float bb2_0 = b2[lh * Dd + n0 + lr];
  const float bb2_1 = b2[lh * Dd + n0 + 16 + lr];

  f32x4 acc[4][2];
#pragma unroll
  for (int mt = 0; mt < 4; ++mt) {
    acc[mt][0] = (f32x4){bb1_0, bb1_0, bb1_0, bb1_0};
    acc[mt][1] = (f32x4){bb1_1, bb1_1, bb1_1, bb1_1};
  }

  __syncthreads();   // drains DMA + W loads; x tile visible

  // ---------------- GEMM1: H = gelu(X @ W1 + b1) ----------------
#pragma unroll
  for (int ks = 0; ks < 4; ++ks) {
    bf16x8 af[4];
#pragma unroll
    for (int mt = 0; mt < 4; ++mt) {
      const int row = mt * 16 + lr;
      const int c0  = ks * 8 + lg * 2;
      const int m   = row & 15;
      const float4 lo = *(const float4*)(smem + row * 512 + ((c0)     ^ m) * 16);
      const float4 hi = *(const float4*)(smem + row * 512 + ((c0 + 1) ^ m) * 16);
      bf16x8 a;
      a[0] = f2bf(lo.x); a[1] = f2bf(lo.y); a[2] = f2bf(lo.z); a[3] = f2bf(lo.w);
      a[4] = f2bf(hi.x); a[5] = f2bf(hi.y); a[6] = f2bf(hi.z); a[7] = f2bf(hi.w);
      af[mt] = a;
    }
#pragma unroll
    for (int mt = 0; mt < 4; ++mt)
#pragma unroll
      for (int nt = 0; nt < 2; ++nt)
        acc[mt][nt] = __builtin_amdgcn_mfma_f32_16x16x32_bf16(af[mt], bw1[ks][nt], acc[mt][nt], 0, 0, 0);
  }

  // GELU in regs, then overlay-write H
  short hv[4][2][4];
#pragma unroll
  for (int mt = 0; mt < 4; ++mt)
#pragma unroll
    for (int nt = 0; nt < 2; ++nt)
#pragma unroll
      for (int r = 0; r < 4; ++r)
        hv[mt][nt][r] = f2bf(gelu_fast(acc[mt][nt][r]));

  __syncthreads();   // all waves done reading x LDS -> safe to overlay H

#pragma unroll
  for (int mt = 0; mt < 4; ++mt)
#pragma unroll
    for (int nt = 0; nt < 2; ++nt) {
      const int e = n0 + nt * 16 + lr;
#pragma unroll
      for (int r = 0; r < 4; ++r) {
        const int b = mt * 16 + lg * 4 + r;    // C/D row = (lane>>4)*4 + reg
        const int off = (b * 256 + e * 2) ^ ((b & 7) << 4);
        *(short*)(smem + off) = hv[mt][nt][r];
      }
    }
  __syncthreads();   // H visible

  // ---------------- GEMM2: out = H @ W2 + b2 (W2 in regs) ----------
  f32x4 acc2[4][2];
#pragma unroll
  for (int mt = 0; mt < 4; ++mt) {
    acc2[mt][0] = (f32x4){bb2_0, bb2_0, bb2_0, bb2_0};
    acc2[mt][1] = (f32x4){bb2_1, bb2_1, bb2_1, bb2_1};
  }

#pragma unroll
  for (int ks = 0; ks < 4; ++ks) {
    const int k2 = (ks * 32 + lg * 8) * 2;     // byte offset of 16B H granule
#pragma unroll
    for (int mt = 0; mt < 4; ++mt) {
      const int b = mt * 16 + lr;
      const int off = (b * 256 + k2) ^ ((b & 7) << 4);
      bf16x8 a = *(const bf16x8*)(smem + off);
#pragma unroll
      for (int nt = 0; nt < 2; ++nt)
        acc2[mt][nt] = __builtin_amdgcn_mfma_f32_16x16x32_bf16(a, bw2[ks][nt], acc2[mt][nt], 0, 0, 0);
    }
  }

  // epilogue: regular f32 stores (64B segments per 16-lane group)
  {
    float* ob = out + ((size_t)(bt * BT) * LH + lh) * Dd;
#pragma unroll
    for (int mt = 0; mt < 4; ++mt)
#pragma unroll
      for (int nt = 0; nt < 2; ++nt) {
        const int e = n0 + nt * 16 + lr;
#pragma unroll
        for (int r = 0; r < 4; ++r) {
          const int b = mt * 16 + lg * 4 + r;
          ob[(size_t)b * XSTRIDE + e] = acc2[mt][nt][r];
        }
      }
  }
}

// ---------------- fallback (R7 path, no workspace) ----------------
__global__ __launch_bounds__(256, 4) void fused_mlp_f32(
    const float* __restrict__ x, const float* __restrict__ W1,
    const float* __restrict__ b1, const float* __restrict__ W2,
    const float* __restrict__ b2, float* __restrict__ out) {
  __shared__ alignas(16) char smem[BT * Dd * 4];
  const int tid  = threadIdx.x;
  const int lane = tid & 63;
  const int wid  = tid >> 6;
  const int lr   = lane & 15;
  const int lg   = lane >> 4;
  const int bid = blockIdx.x;
  const int lh = (bid & 7) * 128 + (bid >> 6);
  const int bt = (bid >> 3) & 7;
  const float* w1 = W1 + (size_t)lh * (Dd * Dd);
  const float* w2 = W2 + (size_t)lh * (Dd * Dd);
  const int n0 = wid * 32;
  {
    const float* xblk = x + ((size_t)(bt * BT) * LH + lh) * Dd;
#pragma unroll
    for (int i = 0; i < 8; ++i) {
      const int slot = wid * 8 + i;
      const int row  = slot * 2 + (lane >> 5);
      const int cp   = lane & 31;
      const int c    = cp ^ (row & 15);
      const float* g = xblk + (size_t)row * XSTRIDE + c * 4;
      __builtin_amdgcn_global_load_lds((gu32*)g, (lu32*)(smem + slot * 1024), 16, 0, 0);
    }
  }
  const float bb1_0 = b1[lh * Dd + n0 + lr];
  const float bb1_1 = b1[lh * Dd + n0 + 16 + lr];
  const float bb2_0 = b2[lh * Dd + n0 + lr];
  const float bb2_1 = b2[lh * Dd + n0 + 16 + lr];
  bf16x8 bw1[2];
  {
    const int k0 = lg * 8;
#pragma unroll
    for (int nt = 0; nt < 2; ++nt) {
      const float* wp = w1 + (size_t)k0 * Dd + n0 + nt * 16 + lr;
      bf16x8 b;
#pragma unroll
      for (int j = 0; j < 8; ++j) b[j] = f2bf(wp[j * Dd]);
      bw1[nt] = b;
    }
  }
  f32x4 acc[4][2];
#pragma unroll
  for (int mt = 0; mt < 4; ++mt) {
    acc[mt][0] = (f32x4){bb1_0, bb1_0, bb1_0, bb1_0};
    acc[mt][1] = (f32x4){bb1_1, bb1_1, bb1_1, bb1_1};
  }
  bf16x8 bw2[4][2];
  __syncthreads();
#pragma unroll
  for (int ks = 0; ks < 4; ++ks) {
    bf16x8 bw1n[2];
    if (ks < 3) {
      const int k0 = (ks + 1) * 32 + lg * 8;
#pragma unroll
      for (int nt = 0; nt < 2; ++nt) {
        const float* wp = w1 + (size_t)k0 * Dd + n0 + nt * 16 + lr;
        bf16x8 b;
#pragma unroll
        for (int j = 0; j < 8; ++j) b[j] = f2bf(wp[j * Dd]);
        bw1n[nt] = b;
      }
    }
    {
      const int k0 = ks * 32 + lg * 8;
#pragma unroll
      for (int nt = 0; nt < 2; ++nt) {
        const float* wp = w2 + (size_t)k0 * Dd + n0 + nt * 16 + lr;
        bf16x8 b;
#pragma unroll
        for (int j = 0; j < 8; ++j) b[j] = f2bf(wp[j * Dd]);
        bw2[ks][nt] = b;
      }
    }
    bf16x8 af[4];
#pragma unroll
    for (int mt = 0; mt < 4; ++mt) {
      const int row = mt * 16 + lr;
      const int c0  = ks * 8 + lg * 2;
      const int m   = row & 15;
      const float4 lo = *(const float4*)(smem + row * 512 + ((c0)     ^ m) * 16);
      const float4 hi = *(const float4*)(smem + row * 512 + ((c0 + 1) ^ m) * 16);
      bf16x8 a;
      a[0] = f2bf(lo.x); a[1] = f2bf(lo.y); a[2] = f2bf(lo.z); a[3] = f2bf(lo.w);
      a[4] = f2bf(hi.x); a[5] = f2bf(hi.y); a[6] = f2bf(hi.z); a[7] = f2bf(hi.w);
      af[mt] = a;
    }
#pragma unroll
    for (int mt = 0; mt < 4; ++mt)
#pragma unroll
      for (int nt = 0; nt < 2; ++nt)
        acc[mt][nt] = __builtin_amdgcn_mfma_f32_16x16x32_bf16(af[mt], bw1[nt], acc[mt][nt], 0, 0, 0);
    bw1[0] = bw1n[0];
    bw1[1] = bw1n[1];
  }
  short hv[4][2][4];
#pragma unroll
  for (int mt = 0; mt < 4; ++mt)
#pragma unroll
    for (int nt = 0; nt < 2; ++nt)
#pragma unroll
      for (int r = 0; r < 4; ++r)
        hv[mt][nt][r] = f2bf(gelu_fast(acc[mt][nt][r]));
  __syncthreads();
#pragma unroll
  for (int mt = 0; mt < 4; ++mt)
#pragma unroll
    for (int nt = 0; nt < 2; ++nt) {
      const int e = n0 + nt * 16 + lr;
#pragma unroll
      for (int r = 0; r < 4; ++r) {
        const int b = mt * 16 + lg * 4 + r;
        const int off = (b * 256 + e * 2) ^ ((b & 7) << 4);
        *(short*)(smem + off) = hv[mt][nt][r];
      }
    }
  __syncthreads();
  f32x4 acc2[4][2];
#pragma unroll
  for (int mt = 0; mt < 4; ++mt) {
    acc2[mt][0] = (f32x4){bb2_0, bb2_0, bb2_0, bb2_0};
    acc2[mt][1] = (f32x4){bb2_1, bb2_1, bb2_1, bb2_1};
  }
#pragma unroll
  for (int ks = 0; ks < 4; ++ks) {
    const int k2 = (ks * 32 + lg * 8) * 2;
#pragma unroll
    for (int mt = 0; mt < 4; ++mt) {
      const int b = mt * 16 + lr;
      const int off = (b * 256 + k2) ^ ((b & 7) << 4);
      bf16x8 a = *(const bf16x8*)(smem + off);
#pragma unroll
      for (int nt = 0; nt < 2; ++nt)
        acc2[mt][nt] = __builtin_amdgcn_mfma_f32_16x16x32_bf16(a, bw2[ks][nt], acc2[mt][nt], 0, 0, 0);
    }
  }
  {
    float* ob = out + ((size_t)(bt * BT) * LH + lh) * Dd;
#pragma unroll
    for (int mt = 0; mt < 4; ++mt)
#pragma unroll
      for (int nt = 0; nt < 2; ++nt) {
        const int e = n0 + nt * 16 + lr;
#pragma unroll
        for (int r = 0; r < 4; ++r) {
          const int b = mt * 16 + lg * 4 + r;
          ob[(size_t)b * XSTRIDE + e] = acc2[mt][nt][r];
        }
      }
  }
}

extern "C" void kernel_launch(void* const* d_in, const int* in_sizes, int n_in,
                              void* d_out, int out_size, void* d_ws, size_t ws_size,
                              hipStream_t stream) {
  (void)in_sizes; (void)n_in; (void)out_size;
  const float* x  = (const float*)d_in[0];
  const float* W1 = (const float*)d_in[1];
  const float* b1 = (const float*)d_in[2];
  const float* W2 = (const float*)d_in[3];
  const float* b2 = (const float*)d_in[4];
  float* out = (float*)d_out;
  const size_t need = (size_t)LH * WB_PER_LH;   // 64 MiB
  if (ws_size >= need) {
    repack_w<<<dim3(LH), dim3(256), 0, stream>>>(W1, W2, (char*)d_ws);
    fused_mlp_wb<<<dim3(8192), dim3(256), 0, stream>>>(x, (const char*)d_ws, b1, b2, out);
  } else {
    fused_mlp_f32<<<dim3(8192), dim3(256), 0, stream>>>(x, W1, b1, W2, b2, out);
  }
}

// Round 9
// 150.326 us; speedup vs baseline: 2.2872x; 1.2359x over previous
//
#include <hip/hip_runtime.h>
#include <cstdint>
#include <cstddef>

// x[B=512, L=32, H=32, D=128]; per (l,h): Linear(128->128) -> GELU -> Linear(128->128)
// Persistent-per-lh: one block owns all 8 batch-tiles of one (l,h); W gathered
// to regs ONCE per block (R8's repack prepass amortized away); x DMA
// double-buffered across tiles.
#define LH      1024
#define Dd      128
#define BT      64            // batch rows per tile -> 32 KB f32 in LDS
#define NTILE   8             // 512 / 64
#define XSTRIDE (LH * Dd)

typedef __attribute__((ext_vector_type(8))) short bf16x8;
typedef __attribute__((ext_vector_type(4))) float f32x4;
typedef const __attribute__((address_space(1))) uint32_t gu32;
typedef __attribute__((address_space(3))) uint32_t lu32;

static __device__ __forceinline__ short f2bf(float f) {
  return __builtin_bit_cast(short, (__bf16)f);
}

// tanh-form GELU as one sigmoid; |diff| vs erf-gelu ~3e-3 << 0.185 threshold
static __device__ __forceinline__ float gelu_fast(float v) {
  float v2 = v * v;
  float u2 = v * (1.5957691216f + 0.0713548163f * v2);
  return v / (1.0f + __expf(-u2));
}

__global__ __launch_bounds__(256, 2) void fused_mlp_persist(
    const float* __restrict__ x, const float* __restrict__ W1,
    const float* __restrict__ b1, const float* __restrict__ W2,
    const float* __restrict__ b2, float* __restrict__ out) {
  // 2 ping-pong buffers. Each: x f32 [64 rows][32 chunks of 16B], chunk-index
  // XOR-swizzled on the GLOBAL source addr (global_load_lds writes LDS
  // linearly, m104/m173). H bf16 [64][128] overlays bytes 0..16K of the
  // CURRENT buffer after GEMM1's reads are barrier-complete.
  __shared__ alignas(16) char smem[2][BT * Dd * 4];   // 64 KB -> 2 blocks/CU

  const int tid  = threadIdx.x;
  const int lane = tid & 63;
  const int wid  = tid >> 6;     // 4 waves, each owns 32 N-columns
  const int lr   = lane & 15;
  const int lg   = lane >> 4;

  const int lh = blockIdx.x;     // W reuse is intra-block; no swizzle needed
  const int n0 = wid * 32;

  const float* w1  = W1 + (size_t)lh * (Dd * Dd);
  const float* w2  = W2 + (size_t)lh * (Dd * Dd);
  const float* xlh = x   + (size_t)lh * Dd;
  float*       olh = out + (size_t)lh * Dd;

  // stage tile t into buffer buf: 8 DMA issues/wave, 32 KB in flight
  auto stage = [&](int t, int buf) {
#pragma unroll
    for (int i = 0; i < 8; ++i) {
      const int slot = wid * 8 + i;          // wave-uniform 1KB LDS slot
      const int row  = slot * 2 + (lane >> 5);
      const int cp   = lane & 31;            // chunk position in LDS
      const int c    = cp ^ (row & 15);      // global chunk (bijective swz)
      const float* g = xlh + (size_t)(t * BT + row) * XSTRIDE + c * 4;
      __builtin_amdgcn_global_load_lds((gu32*)g,
                                       (lu32*)(smem[buf] + slot * 1024),
                                       16, 0, 0);
    }
  };

  // ---- prologue: DMA tile 0; gather ALL W fragments to regs (once per
  // block, hidden under the DMA flight); biases.
  stage(0, 0);

  bf16x8 bw1[4][2], bw2[4][2];
#pragma unroll
  for (int ks = 0; ks < 4; ++ks)
#pragma unroll
    for (int nt = 0; nt < 2; ++nt) {
      const float* p1 = w1 + (size_t)(ks * 32 + lg * 8) * Dd + n0 + nt * 16 + lr;
      const float* p2 = w2 + (size_t)(ks * 32 + lg * 8) * Dd + n0 + nt * 16 + lr;
      bf16x8 a, b;
#pragma unroll
      for (int j = 0; j < 8; ++j) { a[j] = f2bf(p1[j * Dd]); b[j] = f2bf(p2[j * Dd]); }
      bw1[ks][nt] = a;
      bw2[ks][nt] = b;
    }

  const float bb1_0 = b1[lh * Dd + n0 + lr];
  const float bb1_1 = b1[lh * Dd + n0 + 16 + lr];
  const float bb2_0 = b2[lh * Dd + n0 + lr];
  const float bb2_1 = b2[lh * Dd + n0 + 16 + lr];

  for (int t = 0; t < NTILE; ++t) {
    const int cur = t & 1;

    // Loop-top barrier: (a) drains DMA(t) -> x[t] visible in smem[cur];
    // (b) proves every wave finished GEMM2(t-1)'s H reads from smem[cur^1],
    // so DMA(t+1) may overwrite it.
    __syncthreads();
    if (t + 1 < NTILE) stage(t + 1, cur ^ 1);

    // ---------------- GEMM1: H = gelu(X @ W1 + b1) ----------------
    f32x4 acc[4][2];
#pragma unroll
    for (int mt = 0; mt < 4; ++mt) {
      acc[mt][0] = (f32x4){bb1_0, bb1_0, bb1_0, bb1_0};
      acc[mt][1] = (f32x4){bb1_1, bb1_1, bb1_1, bb1_1};
    }
#pragma unroll
    for (int ks = 0; ks < 4; ++ks) {
      bf16x8 af[4];
#pragma unroll
      for (int mt = 0; mt < 4; ++mt) {
        const int row = mt * 16 + lr;
        const int c0  = ks * 8 + lg * 2;
        const int m   = row & 15;
        const float4 lo = *(const float4*)(smem[cur] + row * 512 + ((c0)     ^ m) * 16);
        const float4 hi = *(const float4*)(smem[cur] + row * 512 + ((c0 + 1) ^ m) * 16);
        bf16x8 a;
        a[0] = f2bf(lo.x); a[1] = f2bf(lo.y); a[2] = f2bf(lo.z); a[3] = f2bf(lo.w);
        a[4] = f2bf(hi.x); a[5] = f2bf(hi.y); a[6] = f2bf(hi.z); a[7] = f2bf(hi.w);
        af[mt] = a;
      }
#pragma unroll
      for (int mt = 0; mt < 4; ++mt)
#pragma unroll
        for (int nt = 0; nt < 2; ++nt)
          acc[mt][nt] = __builtin_amdgcn_mfma_f32_16x16x32_bf16(af[mt], bw1[ks][nt], acc[mt][nt], 0, 0, 0);
    }

    // GELU in regs, then overlay-write H into smem[cur]
    short hv[4][2][4];
#pragma unroll
    for (int mt = 0; mt < 4; ++mt)
#pragma unroll
      for (int nt = 0; nt < 2; ++nt)
#pragma unroll
        for (int r = 0; r < 4; ++r)
          hv[mt][nt][r] = f2bf(gelu_fast(acc[mt][nt][r]));

    __syncthreads();   // all waves done reading x[cur] -> safe to overlay H

#pragma unroll
    for (int mt = 0; mt < 4; ++mt)
#pragma unroll
      for (int nt = 0; nt < 2; ++nt) {
        const int e = n0 + nt * 16 + lr;
#pragma unroll
        for (int r = 0; r < 4; ++r) {
          const int b = mt * 16 + lg * 4 + r;   // C/D row = (lane>>4)*4 + reg
          const int off = (b * 256 + e * 2) ^ ((b & 7) << 4);
          *(short*)(smem[cur] + off) = hv[mt][nt][r];
        }
      }
    __syncthreads();   // H visible

    // ---------------- GEMM2: out = H @ W2 + b2 (W2 in regs) ----------
    f32x4 acc2[4][2];
#pragma unroll
    for (int mt = 0; mt < 4; ++mt) {
      acc2[mt][0] = (f32x4){bb2_0, bb2_0, bb2_0, bb2_0};
      acc2[mt][1] = (f32x4){bb2_1, bb2_1, bb2_1, bb2_1};
    }
#pragma unroll
    for (int ks = 0; ks < 4; ++ks) {
      const int k2 = (ks * 32 + lg * 8) * 2;   // byte offset of 16B H granule
#pragma unroll
      for (int mt = 0; mt < 4; ++mt) {
        const int b = mt * 16 + lr;
        const int off = (b * 256 + k2) ^ ((b & 7) << 4);
        bf16x8 a = *(const bf16x8*)(smem[cur] + off);
#pragma unroll
        for (int nt = 0; nt < 2; ++nt)
          acc2[mt][nt] = __builtin_amdgcn_mfma_f32_16x16x32_bf16(a, bw2[ks][nt], acc2[mt][nt], 0, 0, 0);
      }
    }

    // epilogue: f32 stores (64B contiguous per 16-lane group)
    {
      float* ob = olh + (size_t)(t * BT) * XSTRIDE;
#pragma unroll
      for (int mt = 0; mt < 4; ++mt)
#pragma unroll
        for (int nt = 0; nt < 2; ++nt) {
          const int e = n0 + nt * 16 + lr;
#pragma unroll
          for (int r = 0; r < 4; ++r) {
            const int b = mt * 16 + lg * 4 + r;
            ob[(size_t)b * XSTRIDE + e] = acc2[mt][nt][r];
          }
        }
    }
  }
}

extern "C" void kernel_launch(void* const* d_in, const int* in_sizes, int n_in,
                              void* d_out, int out_size, void* d_ws, size_t ws_size,
                              hipStream_t stream) {
  (void)in_sizes; (void)n_in; (void)d_ws; (void)ws_size; (void)out_size;
  const float* x  = (const float*)d_in[0];
  const float* W1 = (const float*)d_in[1];
  const float* b1 = (const float*)d_in[2];
  const float* W2 = (const float*)d_in[3];
  const float* b2 = (const float*)d_in[4];
  float* out = (float*)d_out;
  fused_mlp_persist<<<dim3(LH), dim3(256), 0, stream>>>(x, W1, b1, W2, b2, out);
}